// Round 17
// baseline (2532.692 us; speedup 1.0000x reference)
//
#include <hip/hip_runtime.h>
#include <math.h>

#define Bq 16
#define Tq 32
#define Wq 128
#define Rq 4
#define Nq 512
#define Mq 128
#define DINq 768
#define XIDq 919
#define BTWq (Bq*Tq*Wq)

// per-team payload arena (floats)
#define TSTRIDE 31232
#define TF_FW    0        // [8][4*512] fw partials
#define TF_BW    16384    // [4*512]
#define TF_RCA   18432    // [4*512] raw rca scores
#define TF_RW    20480    // [4*512]
#define TF_PR    22528    // [8][512] reads partials
#define TF_WC    26624    // [512] raw wca scores
#define TF_WW    27136    // [512]
#define TF_PREC  27648    // [2][512]
#define TF_XI    28672    // [920]
#define TF_ZP    29696    // [8][128] z-read partials
#define TF_CNT   30720    // counters

struct P {
  const float *X, *hs0, *mem0;
  const int *rst;
  const float *Wb,*bb,*Wff1,*bff1,*Wff2,*bff2,*Wta,*bta,*Wtb,*btb,*Wv,*bv,*Wr,*br,*Wxi,*bxi;
  float *out;
  float *rdh,*teams;
  float *WbT,*Wff1T,*Wff2T,*WtaT,*WtbT,*WvT,*WrT,*WxiT;
};

__device__ __forceinline__ float dot4(float4 a, float4 b){
  return a.x*b.x + a.y*b.y + a.z*b.z + a.w*b.w;
}
__device__ __forceinline__ float sigf(float x){ return 1.f/(1.f+expf(-x)); }
__device__ __forceinline__ float oneplusf(float x){ return 1.f + log1pf(expf(x) + 1e-6f); }

__device__ __forceinline__ void pst(float* p, float v){
  __hip_atomic_store(p, v, __ATOMIC_RELAXED, __HIP_MEMORY_SCOPE_AGENT);
}
__device__ __forceinline__ float pld(float* p){
  return __hip_atomic_load(p, __ATOMIC_RELAXED, __HIP_MEMORY_SCOPE_AGENT);
}
__device__ __forceinline__ void bump(unsigned* f){
  __syncthreads();                      // drains all threads' payload stores
  if (threadIdx.x==0)
    __hip_atomic_fetch_add(f, 1u, __ATOMIC_RELAXED, __HIP_MEMORY_SCOPE_AGENT);
}
__device__ __forceinline__ void waitge(unsigned* f, unsigned v){
  if (threadIdx.x==0){
    while (__hip_atomic_load(f, __ATOMIC_RELAXED, __HIP_MEMORY_SCOPE_AGENT) < v)
      __builtin_amdgcn_s_sleep(1);
  }
  __syncthreads();
}

__device__ __forceinline__ float wave_sum64(float v){
  #pragma unroll
  for (int m=32;m>=1;m>>=1) v += __shfl_xor(v, m, 64);
  return v;
}
__device__ __forceinline__ float wave_max64(float v){
  #pragma unroll
  for (int m=32;m>=1;m>>=1) v = fmaxf(v, __shfl_xor(v, m, 64));
  return v;
}
__device__ __forceinline__ float blk_sum(float v, float* s8){
  int w = threadIdx.x>>6;
  v = wave_sum64(v);
  if ((threadIdx.x&63)==0) s8[w] = v;
  __syncthreads();
  float r = s8[0]+s8[1]+s8[2]+s8[3]+s8[4]+s8[5]+s8[6]+s8[7];
  __syncthreads();
  return r;
}
__device__ __forceinline__ float blk_max(float v, float* s8){
  int w = threadIdx.x>>6;
  v = wave_max64(v);
  if ((threadIdx.x&63)==0) s8[w] = v;
  __syncthreads();
  float r = s8[0];
  #pragma unroll
  for (int q=1;q<8;q++) r = fmaxf(r, s8[q]);
  __syncthreads();
  return r;
}
__device__ __forceinline__ float red_cg(float v){
  v += __shfl_xor(v, 1, 8);
  v += __shfl_xor(v, 2, 8);
  v += __shfl_xor(v, 4, 8);
  return v;
}

// ---------- k_init: weight transposes + zero team arenas ----------
__global__ __launch_bounds__(256) void k_init(P p){
  int bid=blockIdx.x, tid=threadIdx.x;
  if (bid<8){ int idx=bid*256+tid, st=8*256;
    for (int k=idx;k<DINq*Wq;k+=st){ int j=k/DINq,i=k%DINq; p.WbT[k]=p.Wb[i*Wq+j]; }
  } else if (bid<10){ int idx=(bid-8)*256+tid, st=2*256;
    for (int k=idx;k<Wq*Wq;k+=st){ int j=k/Wq,i=k%Wq; p.Wff1T[k]=p.Wff1[i*Wq+j]; }
  } else if (bid<12){ int idx=(bid-10)*256+tid, st=2*256;
    for (int k=idx;k<Wq*Wq;k+=st){ int j=k/Wq,i=k%Wq; p.Wff2T[k]=p.Wff2[i*Wq+j]; }
  } else if (bid<14){ int idx=(bid-12)*256+tid, st=2*256;
    for (int k=idx;k<Wq*Wq;k+=st){ int j=k/Wq,i=k%Wq; p.WtaT[k]=p.Wta[i*Wq+j]; }
  } else if (bid<16){ int idx=(bid-14)*256+tid, st=2*256;
    for (int k=idx;k<Wq*Wq;k+=st){ int j=k/Wq,i=k%Wq; p.WtbT[k]=p.Wtb[i*Wq+j]; }
  } else if (bid<18){ int idx=(bid-16)*256+tid, st=2*256;
    for (int k=idx;k<Wq*Wq;k+=st){ int j=k/Wq,i=k%Wq; p.WvT[k]=p.Wv[i*Wq+j]; }
  } else if (bid<22){ int idx=(bid-18)*256+tid, st=4*256;
    for (int k=idx;k<Rq*Wq*Wq;k+=st){ int j=k/(Rq*Wq),i=k%(Rq*Wq); p.WrT[k]=p.Wr[i*Wq+j]; }
  } else if (bid<30){ int idx=(bid-22)*256+tid, st=8*256;
    for (int k=idx;k<XIDq*Wq;k+=st){ int f=k/Wq,i=k%Wq; p.WxiT[k]=p.Wxi[i*XIDq+f]; }
  } else if (bid<38){ int idx=(bid-30)*256+tid, st=8*256;
    for (int k=idx;k<16*TSTRIDE;k+=st) p.teams[k]=0.f;
  }
}

// ---------- k_run: 16 teams x (1 alpha + 8 link blocks) ----------
// r16 + split CNT_LNK/CNT_FW (early fw/bw pull) + ZP z-partials + deferred rdh.
__global__ __launch_bounds__(512,2) void k_run(P p){
  const int tid=threadIdx.x, bid=blockIdx.x;
  const bool isA = (bid<16);
  const int team = isA ? bid : ((bid-16)>>3);
  const int g    = isA ? 0   : ((bid-16)&7);
  const int b=team;
  const int w=tid>>6, l=tid&63;
  float* T = p.teams + (size_t)team*TSTRIDE;
  unsigned* C = (unsigned*)(T+TF_CNT);
  unsigned* CNT_FW=C+0; unsigned* FLAG_RW=C+32; unsigned* CNT_RD=C+64;
  unsigned* FLAG_XI=C+96; unsigned* CNT_WC=C+128; unsigned* FLAG_WW=C+160;
  unsigned* CNT_LNK=C+192;

  __shared__ __align__(16) float rwl[Rq*Nq];
  __shared__ __align__(16) float xil[XIDq+9];
  __shared__ __align__(16) float wwl[Nq];
  __shared__ __align__(16) float precl[Nq];
  __shared__ __align__(16) float usage[Nq];
  __shared__ __align__(16) float uarr[Nq];
  __shared__ __align__(16) float cpl[Nq];
  __shared__ __align__(16) int   sidx[Nq];
  __shared__ __align__(16) float wcas[Nq];     // alpha: wca | links: prl
  __shared__ __align__(16) float inv[DINq];
  __shared__ __align__(16) float zl[Wq];
  __shared__ __align__(16) float hsl[Wq];
  __shared__ __align__(16) float acc4[4*Wq];
  __shared__ __align__(16) float scrA[Rq*Nq]; // alpha: rcl | links: fwacc
  __shared__ __align__(16) float scrB[Rq*Nq]; // alpha: fwl
  __shared__ __align__(16) float scrC[Rq*Nq]; // alpha: bwl
  __shared__ float s8[8];

  if (isA){
    // ================= ALPHA =================
    for (int i=tid;i<Rq*Nq;i+=512) rwl[i]=0.f;
    usage[tid]=0.f; precl[tid]=0.f; wwl[tid]=0.f;
    if (tid<Wq) hsl[tid]=p.hs0[b*Wq+tid];
    __syncthreads();

    for (int t=0;t<=Tq;t++){
      // ---- combine rw(t-1): fw/bw pulled early under CNT_LNK ----
      if (t>0){
        float* rcl=scrA; float* fwl=scrB; float* bwl=scrC;
        waitge(CNT_LNK, 8u*(unsigned)t);
        #pragma unroll
        for (int k=0;k<4;k++){
          int idx=tid+k*512;
          float f=0.f;
          #pragma unroll
          for (int gg=0;gg<8;gg++) f+=pld(T+TF_FW+gg*2048+idx);
          fwl[idx]=f;
          bwl[idx]=pld(T+TF_BW+idx);
        }
        waitge(CNT_FW, 8u*(unsigned)t);
        #pragma unroll
        for (int k=0;k<4;k++){
          int idx=tid+k*512;
          rcl[idx]=pld(T+TF_RCA+idx);
        }
        __syncthreads();
        #pragma unroll
        for (int r=0;r<Rq;r++){
          float v=rcl[r*Nq+tid];
          float mx=blk_max(v,s8);
          float e=expf(v-mx);
          float se=blk_sum(e,s8);
          rcl[r*Nq+tid]=e/se;
        }
        __syncthreads();
        #pragma unroll
        for (int k=0;k<4;k++){
          int idx=tid+k*512, r=idx>>9;
          float m0=xil[904+r*3],m1=xil[905+r*3],m2=xil[906+r*3];
          float mm=fmaxf(m0,fmaxf(m1,m2));
          float e0=expf(m0-mm),e1=expf(m1-mm),e2=expf(m2-mm);
          float es=e0+e1+e2;
          float rwv=(e0*bwl[idx]+e1*rcl[idx]+e2*fwl[idx])/es;
          rwl[idx]=rwv;
          pst(T+TF_RW+idx,rwv);
        }
      } else {
        #pragma unroll
        for (int k=0;k<4;k++){ int idx=tid+k*512; rwl[idx]=0.f; pst(T+TF_RW+idx,0.f); }
      }
      bump(FLAG_RW);
      // ---- zpart (dead window while links compute PR): x + keep*hs cols ----
      if (t<Tq){
        float keep=1.f-(float)p.rst[b*Tq+t];
        if (tid<Wq){ inv[tid]=p.X[((size_t)b*Tq+t)*Wq+tid]; inv[Wq+Nq+tid]=keep*hsl[tid]; }
        __syncthreads();
        int j=tid>>2,q=tid&3;
        const float4* w4=(const float4*)(p.WbT+(size_t)j*DINq);
        const float4* i4=(const float4*)inv;
        float a=0.f;
        #pragma unroll
        for (int c=q;c<32;c+=4) a+=dot4(w4[c],i4[c]);
        #pragma unroll
        for (int c=160+q;c<192;c+=4) a+=dot4(w4[c],i4[c]);
        a+=__shfl_xor(a,1,4); a+=__shfl_xor(a,2,4);
        if (q==0) zl[j]=a+p.bb[j];
      }
      // ---- z-read contribution via ZP partials ----
      waitge(CNT_RD, 8u*(unsigned)(t+1));
      if (t==Tq){
        // final rdh(t-1) from PR, then done
        float s=0.f;
        #pragma unroll
        for (int gg=0;gg<8;gg++) s+=pld(T+TF_PR+gg*512+tid);
        p.rdh[((size_t)b*Tq+(Tq-1))*Nq+tid]=s;
        break;
      }
      if (tid<Wq){
        float zr=0.f;
        #pragma unroll
        for (int gg=0;gg<8;gg++) zr+=pld(T+TF_ZP+gg*128+tid);
        float z=zl[tid]+zr;
        zl[tid]=z*sigf(z);
      }
      __syncthreads();
      // ---- hs ----
      { int which=tid>>7,j=tid&127;
        const float* Wg=(which==0)?p.Wff1T:(which==1)?p.Wff2T:(which==2)?p.WtaT:p.WtbT;
        const float4* w4=(const float4*)(Wg+(size_t)j*Wq);
        const float4* z4=(const float4*)zl;
        float a=0.f;
        #pragma unroll 8
        for (int c=0;c<32;c++) a+=dot4(w4[c],z4[c]);
        acc4[which*Wq+j]=a;
      }
      __syncthreads();
      if (tid<Wq){
        float a1=acc4[tid]+p.bff1[tid],a2=acc4[Wq+tid]+p.bff2[tid];
        float aa=acc4[2*Wq+tid]+p.bta[tid],ab=acc4[3*Wq+tid]+p.btb[tid];
        float ti=sigf(aa*(float)t+ab);
        float h=a1*(1.f-ti)+ti*a2;
        hsl[tid]=h;
        p.out[BTWq+((size_t)b*Tq+t)*Wq+tid]=h;
      }
      __syncthreads();
      // ---- xi WK: write_key + scalars, publish early ----
      { const float4* h4=(const float4*)hsl;
        { int o=tid>>2, q=tid&3; int f=512+o;
          const float4* w4=(const float4*)(p.WxiT+(size_t)f*Wq);
          float a=0.f;
          #pragma unroll
          for (int c=q;c<32;c+=4) a+=dot4(w4[c],h4[c]);
          a+=__shfl_xor(a,1,4); a+=__shfl_xor(a,2,4);
          if (q==0){ a+=p.bxi[f]; xil[f]=a; pst(T+TF_XI+f,a); }
        }
        if (tid<92){ int o=tid>>2, q=tid&3; int f=896+o;
          const float4* w4=(const float4*)(p.WxiT+(size_t)f*Wq);
          float a=0.f;
          #pragma unroll
          for (int c=q;c<32;c+=4) a+=dot4(w4[c],h4[c]);
          a+=__shfl_xor(a,1,4); a+=__shfl_xor(a,2,4);
          if (q==0){ a+=p.bxi[f]; xil[f]=a; pst(T+TF_XI+f,a); }
        }
      }
      bump(FLAG_XI);
      // ---- xi rest: read keys + write_vec/erase (links pull under FLAG_WW) ----
      { const float4* h4=(const float4*)hsl;
        { const float4* w4=(const float4*)(p.WxiT+(size_t)tid*Wq);
          float a=p.bxi[tid];
          #pragma unroll 8
          for (int c=0;c<32;c++) a+=dot4(w4[c],h4[c]);
          xil[tid]=a; pst(T+TF_XI+tid,a);
        }
        if (tid<256){ int f=640+tid;
          const float4* w4=(const float4*)(p.WxiT+(size_t)f*Wq);
          float a=p.bxi[f];
          #pragma unroll 8
          for (int c=0;c<32;c++) a+=dot4(w4[c],h4[c]);
          xil[f]=a; pst(T+TF_XI+f,a);
        }
      }
      __syncthreads();
      // ---- usage / rank-sort / cumprod (overlaps links' wca) ----
      int n=tid;
      float ret=1.f;
      #pragma unroll
      for (int r=0;r<Rq;r++) ret*=1.f-sigf(xil[896+r])*rwl[r*Nq+n];
      float uo=usage[n],pw=wwl[n];
      float u=(uo+pw-uo*pw)*ret;
      usage[n]=u; uarr[n]=u;
      __syncthreads();
      int rank=0;
      const float4* u4=(const float4*)uarr;
      #pragma unroll 8
      for (int jj=0;jj<128;jj++){
        float4 vv=u4[jj]; int j0=jj*4;
        rank+=(vv.x<u)||(vv.x==u&&(j0+0)<n);
        rank+=(vv.y<u)||(vv.y==u&&(j0+1)<n);
        rank+=(vv.z<u)||(vv.z==u&&(j0+2)<n);
        rank+=(vv.w<u)||(vv.w==u&&(j0+3)<n);
      }
      sidx[rank]=n;
      __syncthreads();
      int si=sidx[n];
      float sv=uarr[si];
      float x=sv;
      #pragma unroll
      for (int dd=1;dd<64;dd<<=1){ float pr=__shfl_up(x,dd,64); if (l>=dd) x*=pr; }
      if (l==63) s8[w]=x;
      __syncthreads();
      float woff=1.f;
      #pragma unroll
      for (int q=0;q<8;q++) if (q<w) woff*=s8[q];
      x*=woff;
      cpl[n]=x;
      // ---- wca softmax + ww + prec ----
      waitge(CNT_WC, 8u*(unsigned)(t+1));   // contains syncthreads (orders cpl/s8)
      { float v=pld(T+TF_WC+tid);
        float mx=blk_max(v,s8);
        float e=expf(v-mx);
        float se=blk_sum(e,s8);
        wcas[tid]=e/se;
      }
      __syncthreads();
      float alloc=(1.f-u)*cpl[si];          // reference's cp[si[k]] indexing
      float ag=sigf(xil[917]),wg=sigf(xil[918]);
      float wwv=wg*(ag*alloc+(1.f-ag)*wcas[n]);
      wwl[n]=wwv;
      pst(T+TF_WW+n,wwv);
      float wsum=blk_sum(wwv,s8);
      float pn=(1.f-wsum)*precl[n]+wwv;
      precl[n]=pn;
      pst(T+TF_PREC+(t&1)*Nq+n,pn);
      bump(FLAG_WW);
      // ---- deferred: rdh(t-1) from PR (overlaps links' ph6+mem/rca) ----
      if (t>0){
        float s=0.f;
        #pragma unroll
        for (int gg=0;gg<8;gg++) s+=pld(T+TF_PR+gg*512+tid);
        p.rdh[((size_t)b*Tq+(t-1))*Nq+tid]=s;
      }
    }
  } else {
    // ================= LINK =================
    const int rg=l>>3, cg=l&7;
    const int n_own=g*64+w*8+rg;
    const int c0=cg*16;
    float4 m4[4]; float nrm;
    { const float4* src=(const float4*)(p.mem0+((size_t)b*Nq+n_own)*Mq+c0);
      float s=0.f;
      #pragma unroll
      for (int i=0;i<4;i++){ m4[i]=src[i]; s+=dot4(m4[i],m4[i]); }
      nrm=sqrtf(red_cg(s));
    }
    float Lreg[8][8];
    #pragma unroll
    for (int rr=0;rr<8;rr++)
      #pragma unroll
      for (int q=0;q<8;q++) Lreg[rr][q]=0.f;

    for (int t=0;t<=Tq;t++){
      // ---- reads partial ----
      waitge(FLAG_RW, (unsigned)(t+1));
      for (int i=tid;i<Rq*Nq;i+=512) rwl[i]=pld(T+TF_RW+i);
      float* prl=wcas;
      prl[tid]=0.f;
      __syncthreads();
      #pragma unroll
      for (int r=0;r<Rq;r++){
        float rwn=rwl[r*Nq+n_own];
        #pragma unroll
        for (int i=0;i<4;i++){
          float ax=rwn*m4[i].x, ay=rwn*m4[i].y, az=rwn*m4[i].z, aw=rwn*m4[i].w;
          ax+=__shfl_xor(ax,8,64); ax+=__shfl_xor(ax,16,64); ax+=__shfl_xor(ax,32,64);
          ay+=__shfl_xor(ay,8,64); ay+=__shfl_xor(ay,16,64); ay+=__shfl_xor(ay,32,64);
          az+=__shfl_xor(az,8,64); az+=__shfl_xor(az,16,64); az+=__shfl_xor(az,32,64);
          aw+=__shfl_xor(aw,8,64); aw+=__shfl_xor(aw,16,64); aw+=__shfl_xor(aw,32,64);
          if (rg==0){
            atomicAdd(&prl[r*Wq+c0+i*4+0],ax);
            atomicAdd(&prl[r*Wq+c0+i*4+1],ay);
            atomicAdd(&prl[r*Wq+c0+i*4+2],az);
            atomicAdd(&prl[r*Wq+c0+i*4+3],aw);
          }
        }
      }
      __syncthreads();
      pst(T+TF_PR+g*512+tid, prl[tid]);
      // ---- ZP: fold own reads-partial into z-space ----
      { int j=tid>>2, q=tid&3;
        const float4* w4=(const float4*)(p.WbT+(size_t)j*DINq);
        const float4* pr4=(const float4*)prl;
        float a=0.f;
        #pragma unroll
        for (int c=0;c<32;c++) a+=dot4(w4[32+q*32+c], pr4[q*32+c]);
        a+=__shfl_xor(a,1,4); a+=__shfl_xor(a,2,4);
        if (q==0) pst(T+TF_ZP+g*128+j, a);
      }
      bump(CNT_RD);
      if (t==Tq) break;
      // ---- xi WK pull + wca score ----
      waitge(FLAG_XI, (unsigned)(t+1));
      if (tid<Wq) xil[512+tid]=pld(T+TF_XI+512+tid);
      if (tid<23) xil[896+tid]=pld(T+TF_XI+896+tid);
      __syncthreads();
      float keep=1.f-(float)p.rst[b*Tq+t];
      { float kk=(tid<Wq)? xil[512+tid]*xil[512+tid]:0.f;
        float kn=sqrtf(blk_sum(kk,s8));
        const float4* k4=(const float4*)(xil+512);
        float d=0.f;
        #pragma unroll
        for (int i=0;i<4;i++) d+=dot4(k4[cg*4+i],m4[i]);
        d=red_cg(d);
        float wstr=oneplusf(xil[916]);
        float sim=(keep*d)/(kn*(keep*nrm)+1e-6f);
        if (cg==0) pst(T+TF_WC+n_own, wstr*sim);
      }
      bump(CNT_WC);
      // ---- prec prefetch, wait ww, pull ww + xi rest ----
      precl[tid]=pld(T+TF_PREC+((t&1)^1)*Nq+tid);
      waitge(FLAG_WW,(unsigned)(t+1));
      wwl[tid]=pld(T+TF_WW+tid);
      xil[tid]=pld(T+TF_XI+tid);
      if (tid<256) xil[640+tid]=pld(T+TF_XI+640+tid);
      __syncthreads();
      // ---- link update (registers) + fw/bw ----
      { float* fwacc=scrA;
        int c0p=l*8;
        float ww8[8],pc8[8],pr8[Rq][8];
        *(float4*)&ww8[0]=*(const float4*)&wwl[c0p];   *(float4*)&ww8[4]=*(const float4*)&wwl[c0p+4];
        *(float4*)&pc8[0]=*(const float4*)&precl[c0p]; *(float4*)&pc8[4]=*(const float4*)&precl[c0p+4];
        #pragma unroll
        for (int r=0;r<Rq;r++){
          *(float4*)&pr8[r][0]=*(const float4*)&rwl[r*Nq+c0p];
          *(float4*)&pr8[r][4]=*(const float4*)&rwl[r*Nq+c0p+4];
        }
        float fa[Rq][8];
        #pragma unroll
        for (int r=0;r<Rq;r++)
          #pragma unroll
          for (int q=0;q<8;q++) fa[r][q]=0.f;
        #pragma unroll
        for (int rr=0;rr<8;rr++){
          int n2=g*64+w*8+rr;
          float wwn=wwl[n2];
          float prn[Rq];
          #pragma unroll
          for (int r=0;r<Rq;r++) prn[r]=rwl[r*Nq+n2];
          float bwp[Rq]={0.f,0.f,0.f,0.f};
          #pragma unroll
          for (int q=0;q<8;q++){
            float nv=(1.f-wwn-ww8[q])*Lreg[rr][q]+wwn*pc8[q];
            if (c0p+q==n2) nv=0.f;
            Lreg[rr][q]=nv;
            #pragma unroll
            for (int r=0;r<Rq;r++){ fa[r][q]+=prn[r]*nv; bwp[r]+=pr8[r][q]*nv; }
          }
          #pragma unroll
          for (int mm=1;mm<64;mm<<=1)
            #pragma unroll
            for (int r=0;r<Rq;r++) bwp[r]+=__shfl_xor(bwp[r],mm,64);
          if (l==0){
            #pragma unroll
            for (int r=0;r<Rq;r++) pst(T+TF_BW+r*Nq+n2, bwp[r]);
          }
        }
        // wave-serialized fw accumulation (no LDS atomics)
        for (int k=0;k<8;k++){
          if (w==k){
            #pragma unroll
            for (int r=0;r<Rq;r++)
              #pragma unroll
              for (int q=0;q<8;q++){
                if (k==0) fwacc[r*Nq+c0p+q]=fa[r][q];
                else      fwacc[r*Nq+c0p+q]+=fa[r][q];
              }
          }
          __syncthreads();
        }
        for (int i=tid;i<Rq*Nq;i+=512) pst(T+TF_FW+g*2048+i,fwacc[i]);
      }
      bump(CNT_LNK);   // fw/bw ready — alpha starts its big pull now
      // ---- mem update (registers) + new norm + rca scores ----
      { float wwn=wwl[n_own];
        float s=0.f;
        #pragma unroll
        for (int i=0;i<4;i++){
          float e0=sigf(xil[768+c0+i*4+0]), e1=sigf(xil[768+c0+i*4+1]);
          float e2=sigf(xil[768+c0+i*4+2]), e3=sigf(xil[768+c0+i*4+3]);
          m4[i].x=m4[i].x*keep*(1.f-wwn*e0)+wwn*xil[640+c0+i*4+0];
          m4[i].y=m4[i].y*keep*(1.f-wwn*e1)+wwn*xil[640+c0+i*4+1];
          m4[i].z=m4[i].z*keep*(1.f-wwn*e2)+wwn*xil[640+c0+i*4+2];
          m4[i].w=m4[i].w*keep*(1.f-wwn*e3)+wwn*xil[640+c0+i*4+3];
          s+=dot4(m4[i],m4[i]);
        }
        nrm=sqrtf(red_cg(s));
        float kn4[Rq], rstr[Rq];
        #pragma unroll
        for (int r=0;r<Rq;r++){
          float kk=(tid<Wq)? xil[r*Wq+tid]*xil[r*Wq+tid]:0.f;
          kn4[r]=sqrtf(blk_sum(kk,s8));
          rstr[r]=oneplusf(xil[900+r]);
        }
        #pragma unroll
        for (int r=0;r<Rq;r++){
          const float4* kr=(const float4*)(xil+r*Wq);
          float d=0.f;
          #pragma unroll
          for (int i=0;i<4;i++) d+=dot4(kr[cg*4+i],m4[i]);
          d=red_cg(d);
          float v=rstr[r]*(d/(kn4[r]*nrm+1e-6f));
          if (cg==0) pst(T+TF_RCA+r*Nq+n_own, v);
        }
      }
      bump(CNT_FW);
    }
  }
}

// ---------- k_y: all outputs y[b][t][j] ----------
__global__ __launch_bounds__(512) void k_y(P p){
  int j=blockIdx.x, tid=threadIdx.x;
  __shared__ __align__(16) float wv[Wq];
  __shared__ __align__(16) float wr[Rq*Wq];
  if (tid<Wq) wv[tid]=p.WvT[(size_t)j*Wq+tid];
  wr[tid]=p.WrT[(size_t)j*(Rq*Wq)+tid];
  __syncthreads();
  int b=tid>>5, t=tid&31;
  const float4* h4=(const float4*)(p.out+BTWq+((size_t)b*Tq+t)*Wq);
  const float4* r4=(const float4*)(p.rdh+((size_t)b*Tq+t)*Nq);
  const float4* wv4=(const float4*)wv;
  const float4* wr4=(const float4*)wr;
  float a=0.f;
  #pragma unroll 8
  for (int c=0;c<32;c++) a+=dot4(wv4[c],h4[c]);
  #pragma unroll 8
  for (int c=0;c<128;c++) a+=dot4(wr4[c],r4[c]);
  p.out[((size_t)b*Tq+t)*Wq+j]=a+p.bv[j]+p.br[j];
}

extern "C" void kernel_launch(void* const* d_in, const int* in_sizes, int n_in,
                              void* d_out, int out_size, void* d_ws, size_t ws_size,
                              hipStream_t stream){
  (void)in_sizes; (void)n_in; (void)out_size; (void)ws_size;
  P p;
  p.X    = (const float*)d_in[0];
  p.hs0  = (const float*)d_in[1];
  p.mem0 = (const float*)d_in[2];
  p.rst  = (const int*)d_in[3];
  p.Wb   = (const float*)d_in[4];  p.bb   = (const float*)d_in[5];
  p.Wff1 = (const float*)d_in[6];  p.bff1 = (const float*)d_in[7];
  p.Wff2 = (const float*)d_in[8];  p.bff2 = (const float*)d_in[9];
  p.Wta  = (const float*)d_in[10]; p.bta  = (const float*)d_in[11];
  p.Wtb  = (const float*)d_in[12]; p.btb  = (const float*)d_in[13];
  p.Wv   = (const float*)d_in[14]; p.bv   = (const float*)d_in[15];
  p.Wr   = (const float*)d_in[16]; p.br   = (const float*)d_in[17];
  p.Wxi  = (const float*)d_in[18]; p.bxi  = (const float*)d_in[19];
  p.out  = (float*)d_out;
  float* ws = (float*)d_ws;
  size_t o = 0;
  p.rdh   = ws + o; o += (size_t)Bq*Tq*Nq;    //   262,144
  p.teams = ws + o; o += (size_t)16*TSTRIDE;  //   499,712
  p.WbT   = ws + o; o += (size_t)DINq*Wq;
  p.Wff1T = ws + o; o += (size_t)Wq*Wq;
  p.Wff2T = ws + o; o += (size_t)Wq*Wq;
  p.WtaT  = ws + o; o += (size_t)Wq*Wq;
  p.WtbT  = ws + o; o += (size_t)Wq*Wq;
  p.WvT   = ws + o; o += (size_t)Wq*Wq;
  p.WrT   = ws + o; o += (size_t)Rq*Wq*Wq;
  p.WxiT  = ws + o; o += (size_t)XIDq*Wq;

  hipLaunchKernelGGL(k_init, dim3(38),  dim3(256), 0, stream, p);
  hipLaunchKernelGGL(k_run,  dim3(144), dim3(512), 0, stream, p);
  hipLaunchKernelGGL(k_y,    dim3(128), dim3(512), 0, stream, p);
}

// Round 18
// 2411.341 us; speedup vs baseline: 1.0503x; 1.0503x over previous
//
#include <hip/hip_runtime.h>
#include <math.h>

#define Bq 16
#define Tq 32
#define Wq 128
#define Rq 4
#define Nq 512
#define Mq 128
#define DINq 768
#define XIDq 919
#define BTWq (Bq*Tq*Wq)

// per-team payload arena (floats)
#define TSTRIDE 31232
#define TF_FW    0        // [8][4*512] fw partials
#define TF_BW    16384    // [4*512]
#define TF_RCA   18432    // [4*512] raw rca scores
#define TF_RW    20480    // [4*512]
#define TF_PR    22528    // [8][512] reads partials
#define TF_WC    26624    // [512] raw wca scores
#define TF_WW    27136    // [512]
#define TF_PREC  27648    // [2][512]
#define TF_XI    28672    // [920]
#define TF_CNT   29696    // counters

struct P {
  const float *X, *hs0, *mem0;
  const int *rst;
  const float *Wb,*bb,*Wff1,*bff1,*Wff2,*bff2,*Wta,*bta,*Wtb,*btb,*Wv,*bv,*Wr,*br,*Wxi,*bxi;
  float *out;
  float *rdh,*teams;
  float *WbT,*Wff1T,*Wff2T,*WtaT,*WtbT,*WvT,*WrT,*WxiT;
};

__device__ __forceinline__ float dot4(float4 a, float4 b){
  return a.x*b.x + a.y*b.y + a.z*b.z + a.w*b.w;
}
__device__ __forceinline__ float sigf(float x){ return 1.f/(1.f+expf(-x)); }
__device__ __forceinline__ float oneplusf(float x){ return 1.f + log1pf(expf(x) + 1e-6f); }

__device__ __forceinline__ void pst(float* p, float v){
  __hip_atomic_store(p, v, __ATOMIC_RELAXED, __HIP_MEMORY_SCOPE_AGENT);
}
__device__ __forceinline__ float pld(float* p){
  return __hip_atomic_load(p, __ATOMIC_RELAXED, __HIP_MEMORY_SCOPE_AGENT);
}
__device__ __forceinline__ void bump(unsigned* f){
  __syncthreads();                      // drains all threads' payload stores
  if (threadIdx.x==0)
    __hip_atomic_fetch_add(f, 1u, __ATOMIC_RELAXED, __HIP_MEMORY_SCOPE_AGENT);
}
__device__ __forceinline__ void waitge(unsigned* f, unsigned v){
  if (threadIdx.x==0){
    while (__hip_atomic_load(f, __ATOMIC_RELAXED, __HIP_MEMORY_SCOPE_AGENT) < v)
      __builtin_amdgcn_s_sleep(1);
  }
  __syncthreads();
}

__device__ __forceinline__ float wave_sum64(float v){
  #pragma unroll
  for (int m=32;m>=1;m>>=1) v += __shfl_xor(v, m, 64);
  return v;
}
__device__ __forceinline__ float wave_max64(float v){
  #pragma unroll
  for (int m=32;m>=1;m>>=1) v = fmaxf(v, __shfl_xor(v, m, 64));
  return v;
}
__device__ __forceinline__ float blk_sum(float v, float* s8){
  int w = threadIdx.x>>6;
  v = wave_sum64(v);
  if ((threadIdx.x&63)==0) s8[w] = v;
  __syncthreads();
  float r = s8[0]+s8[1]+s8[2]+s8[3]+s8[4]+s8[5]+s8[6]+s8[7];
  __syncthreads();
  return r;
}
__device__ __forceinline__ float blk_max(float v, float* s8){
  int w = threadIdx.x>>6;
  v = wave_max64(v);
  if ((threadIdx.x&63)==0) s8[w] = v;
  __syncthreads();
  float r = s8[0];
  #pragma unroll
  for (int q=1;q<8;q++) r = fmaxf(r, s8[q]);
  __syncthreads();
  return r;
}
__device__ __forceinline__ float red_cg(float v){
  v += __shfl_xor(v, 1, 8);
  v += __shfl_xor(v, 2, 8);
  v += __shfl_xor(v, 4, 8);
  return v;
}

// ---------- k_init: weight transposes + zero team arenas ----------
__global__ __launch_bounds__(256) void k_init(P p){
  int bid=blockIdx.x, tid=threadIdx.x;
  if (bid<8){ int idx=bid*256+tid, st=8*256;
    for (int k=idx;k<DINq*Wq;k+=st){ int j=k/DINq,i=k%DINq; p.WbT[k]=p.Wb[i*Wq+j]; }
  } else if (bid<10){ int idx=(bid-8)*256+tid, st=2*256;
    for (int k=idx;k<Wq*Wq;k+=st){ int j=k/Wq,i=k%Wq; p.Wff1T[k]=p.Wff1[i*Wq+j]; }
  } else if (bid<12){ int idx=(bid-10)*256+tid, st=2*256;
    for (int k=idx;k<Wq*Wq;k+=st){ int j=k/Wq,i=k%Wq; p.Wff2T[k]=p.Wff2[i*Wq+j]; }
  } else if (bid<14){ int idx=(bid-12)*256+tid, st=2*256;
    for (int k=idx;k<Wq*Wq;k+=st){ int j=k/Wq,i=k%Wq; p.WtaT[k]=p.Wta[i*Wq+j]; }
  } else if (bid<16){ int idx=(bid-14)*256+tid, st=2*256;
    for (int k=idx;k<Wq*Wq;k+=st){ int j=k/Wq,i=k%Wq; p.WtbT[k]=p.Wtb[i*Wq+j]; }
  } else if (bid<18){ int idx=(bid-16)*256+tid, st=2*256;
    for (int k=idx;k<Wq*Wq;k+=st){ int j=k/Wq,i=k%Wq; p.WvT[k]=p.Wv[i*Wq+j]; }
  } else if (bid<22){ int idx=(bid-18)*256+tid, st=4*256;
    for (int k=idx;k<Rq*Wq*Wq;k+=st){ int j=k/(Rq*Wq),i=k%(Rq*Wq); p.WrT[k]=p.Wr[i*Wq+j]; }
  } else if (bid<30){ int idx=(bid-22)*256+tid, st=8*256;
    for (int k=idx;k<XIDq*Wq;k+=st){ int f=k/Wq,i=k%Wq; p.WxiT[k]=p.Wxi[i*XIDq+f]; }
  } else if (bid<38){ int idx=(bid-30)*256+tid, st=8*256;
    for (int k=idx;k<16*TSTRIDE;k+=st) p.teams[k]=0.f;
  }
}

// ---------- k_run: 16 teams x (1 alpha + 8 link blocks) ----------
// r16 structure (zpart-in-gap + split xi publish) + CNT_LNK split:
// links bump CNT_LNK after fw/bw publish (before mem/rca), so alpha's big
// fw/bw pull overlaps links' mem-update+rca tail.
__global__ __launch_bounds__(512,2) void k_run(P p){
  const int tid=threadIdx.x, bid=blockIdx.x;
  const bool isA = (bid<16);
  const int team = isA ? bid : ((bid-16)>>3);
  const int g    = isA ? 0   : ((bid-16)&7);
  const int b=team;
  const int w=tid>>6, l=tid&63;
  float* T = p.teams + (size_t)team*TSTRIDE;
  unsigned* C = (unsigned*)(T+TF_CNT);
  unsigned* CNT_FW=C+0; unsigned* FLAG_RW=C+32; unsigned* CNT_RD=C+64;
  unsigned* FLAG_XI=C+96; unsigned* CNT_WC=C+128; unsigned* FLAG_WW=C+160;
  unsigned* CNT_LNK=C+192;

  __shared__ __align__(16) float rwl[Rq*Nq];
  __shared__ __align__(16) float xil[XIDq+9];
  __shared__ __align__(16) float wwl[Nq];
  __shared__ __align__(16) float precl[Nq];
  __shared__ __align__(16) float usage[Nq];
  __shared__ __align__(16) float uarr[Nq];
  __shared__ __align__(16) float cpl[Nq];
  __shared__ __align__(16) int   sidx[Nq];
  __shared__ __align__(16) float wcas[Nq];     // alpha: wca | links: prl
  __shared__ __align__(16) float inv[DINq];
  __shared__ __align__(16) float zl[Wq];
  __shared__ __align__(16) float hsl[Wq];
  __shared__ __align__(16) float acc4[4*Wq];
  __shared__ __align__(16) float scrA[Rq*Nq]; // alpha: rcl | links: fwacc
  __shared__ __align__(16) float scrB[Rq*Nq]; // alpha: fwl
  __shared__ __align__(16) float scrC[Rq*Nq]; // alpha: bwl
  __shared__ float s8[8];

  if (isA){
    // ================= ALPHA =================
    for (int i=tid;i<Rq*Nq;i+=512) rwl[i]=0.f;
    usage[tid]=0.f; precl[tid]=0.f; wwl[tid]=0.f;
    if (tid<Wq) hsl[tid]=p.hs0[b*Wq+tid];
    __syncthreads();

    for (int t=0;t<=Tq;t++){
      // ---- combine rw(t-1): fw/bw under CNT_LNK (early), rca under CNT_FW ----
      if (t>0){
        float* rcl=scrA; float* fwl=scrB; float* bwl=scrC;
        waitge(CNT_LNK, 8u*(unsigned)t);
        #pragma unroll
        for (int k=0;k<4;k++){
          int idx=tid+k*512;
          float f=0.f;
          #pragma unroll
          for (int gg=0;gg<8;gg++) f+=pld(T+TF_FW+gg*2048+idx);
          fwl[idx]=f;
          bwl[idx]=pld(T+TF_BW+idx);
        }
        waitge(CNT_FW, 8u*(unsigned)t);
        #pragma unroll
        for (int k=0;k<4;k++){
          int idx=tid+k*512;
          rcl[idx]=pld(T+TF_RCA+idx);
        }
        __syncthreads();
        #pragma unroll
        for (int r=0;r<Rq;r++){
          float v=rcl[r*Nq+tid];
          float mx=blk_max(v,s8);
          float e=expf(v-mx);
          float se=blk_sum(e,s8);
          rcl[r*Nq+tid]=e/se;
        }
        __syncthreads();
        #pragma unroll
        for (int k=0;k<4;k++){
          int idx=tid+k*512, r=idx>>9;
          float m0=xil[904+r*3],m1=xil[905+r*3],m2=xil[906+r*3];
          float mm=fmaxf(m0,fmaxf(m1,m2));
          float e0=expf(m0-mm),e1=expf(m1-mm),e2=expf(m2-mm);
          float es=e0+e1+e2;
          float rwv=(e0*bwl[idx]+e1*rcl[idx]+e2*fwl[idx])/es;
          rwl[idx]=rwv;
          pst(T+TF_RW+idx,rwv);
        }
      } else {
        #pragma unroll
        for (int k=0;k<4;k++){ int idx=tid+k*512; rwl[idx]=0.f; pst(T+TF_RW+idx,0.f); }
      }
      bump(FLAG_RW);
      // ---- zpart (dead window while links compute PR): x + keep*hs cols ----
      if (t<Tq){
        float keep=1.f-(float)p.rst[b*Tq+t];
        if (tid<Wq){ inv[tid]=p.X[((size_t)b*Tq+t)*Wq+tid]; inv[Wq+Nq+tid]=keep*hsl[tid]; }
        __syncthreads();
        int j=tid>>2,q=tid&3;
        const float4* w4=(const float4*)(p.WbT+(size_t)j*DINq);
        const float4* i4=(const float4*)inv;
        float a=0.f;
        #pragma unroll
        for (int c=q;c<32;c+=4) a+=dot4(w4[c],i4[c]);
        #pragma unroll
        for (int c=160+q;c<192;c+=4) a+=dot4(w4[c],i4[c]);
        a+=__shfl_xor(a,1,4); a+=__shfl_xor(a,2,4);
        if (q==0) zl[j]=a+p.bb[j];
      }
      // ---- reads(t-1) from PR partials ----
      waitge(CNT_RD, 8u*(unsigned)(t+1));
      if (t>0){
        float s=0.f;
        #pragma unroll
        for (int gg=0;gg<8;gg++) s+=pld(T+TF_PR+gg*512+tid);
        inv[Wq+tid]=s;
        p.rdh[((size_t)b*Tq+(t-1))*Nq+tid]=s;
      } else inv[Wq+tid]=0.f;
      if (t==Tq) break;
      __syncthreads();
      // ---- z complete (reads columns only) ----
      { int j=tid>>2,q=tid&3;
        const float4* w4=(const float4*)(p.WbT+(size_t)j*DINq);
        const float4* i4=(const float4*)inv;
        float a=0.f;
        for (int c=32+q;c<160;c+=4) a+=dot4(w4[c],i4[c]);
        a+=__shfl_xor(a,1,4); a+=__shfl_xor(a,2,4);
        if (q==0){ float z=zl[j]+a; zl[j]=z*sigf(z); }
      }
      __syncthreads();
      // ---- hs ----
      { int which=tid>>7,j=tid&127;
        const float* Wg=(which==0)?p.Wff1T:(which==1)?p.Wff2T:(which==2)?p.WtaT:p.WtbT;
        const float4* w4=(const float4*)(Wg+(size_t)j*Wq);
        const float4* z4=(const float4*)zl;
        float a=0.f;
        #pragma unroll 8
        for (int c=0;c<32;c++) a+=dot4(w4[c],z4[c]);
        acc4[which*Wq+j]=a;
      }
      __syncthreads();
      if (tid<Wq){
        float a1=acc4[tid]+p.bff1[tid],a2=acc4[Wq+tid]+p.bff2[tid];
        float aa=acc4[2*Wq+tid]+p.bta[tid],ab=acc4[3*Wq+tid]+p.btb[tid];
        float ti=sigf(aa*(float)t+ab);
        float h=a1*(1.f-ti)+ti*a2;
        hsl[tid]=h;
        p.out[BTWq+((size_t)b*Tq+t)*Wq+tid]=h;
      }
      __syncthreads();
      // ---- xi WK: write_key + scalars, publish early ----
      { const float4* h4=(const float4*)hsl;
        { int o=tid>>2, q=tid&3; int f=512+o;
          const float4* w4=(const float4*)(p.WxiT+(size_t)f*Wq);
          float a=0.f;
          #pragma unroll
          for (int c=q;c<32;c+=4) a+=dot4(w4[c],h4[c]);
          a+=__shfl_xor(a,1,4); a+=__shfl_xor(a,2,4);
          if (q==0){ a+=p.bxi[f]; xil[f]=a; pst(T+TF_XI+f,a); }
        }
        if (tid<92){ int o=tid>>2, q=tid&3; int f=896+o;
          const float4* w4=(const float4*)(p.WxiT+(size_t)f*Wq);
          float a=0.f;
          #pragma unroll
          for (int c=q;c<32;c+=4) a+=dot4(w4[c],h4[c]);
          a+=__shfl_xor(a,1,4); a+=__shfl_xor(a,2,4);
          if (q==0){ a+=p.bxi[f]; xil[f]=a; pst(T+TF_XI+f,a); }
        }
      }
      bump(FLAG_XI);
      // ---- xi rest: read keys + write_vec/erase (links pull under FLAG_WW) ----
      { const float4* h4=(const float4*)hsl;
        { const float4* w4=(const float4*)(p.WxiT+(size_t)tid*Wq);
          float a=p.bxi[tid];
          #pragma unroll 8
          for (int c=0;c<32;c++) a+=dot4(w4[c],h4[c]);
          xil[tid]=a; pst(T+TF_XI+tid,a);
        }
        if (tid<256){ int f=640+tid;
          const float4* w4=(const float4*)(p.WxiT+(size_t)f*Wq);
          float a=p.bxi[f];
          #pragma unroll 8
          for (int c=0;c<32;c++) a+=dot4(w4[c],h4[c]);
          xil[f]=a; pst(T+TF_XI+f,a);
        }
      }
      __syncthreads();
      // ---- usage / rank-sort / cumprod (overlaps links' wca) ----
      int n=tid;
      float ret=1.f;
      #pragma unroll
      for (int r=0;r<Rq;r++) ret*=1.f-sigf(xil[896+r])*rwl[r*Nq+n];
      float uo=usage[n],pw=wwl[n];
      float u=(uo+pw-uo*pw)*ret;
      usage[n]=u; uarr[n]=u;
      __syncthreads();
      int rank=0;
      const float4* u4=(const float4*)uarr;
      #pragma unroll 8
      for (int jj=0;jj<128;jj++){
        float4 vv=u4[jj]; int j0=jj*4;
        rank+=(vv.x<u)||(vv.x==u&&(j0+0)<n);
        rank+=(vv.y<u)||(vv.y==u&&(j0+1)<n);
        rank+=(vv.z<u)||(vv.z==u&&(j0+2)<n);
        rank+=(vv.w<u)||(vv.w==u&&(j0+3)<n);
      }
      sidx[rank]=n;
      __syncthreads();
      int si=sidx[n];
      float sv=uarr[si];
      float x=sv;
      #pragma unroll
      for (int dd=1;dd<64;dd<<=1){ float pr=__shfl_up(x,dd,64); if (l>=dd) x*=pr; }
      if (l==63) s8[w]=x;
      __syncthreads();
      float woff=1.f;
      #pragma unroll
      for (int q=0;q<8;q++) if (q<w) woff*=s8[q];
      x*=woff;
      cpl[n]=x;
      // ---- wca softmax + ww + prec ----
      waitge(CNT_WC, 8u*(unsigned)(t+1));   // contains syncthreads (orders cpl/s8)
      { float v=pld(T+TF_WC+tid);
        float mx=blk_max(v,s8);
        float e=expf(v-mx);
        float se=blk_sum(e,s8);
        wcas[tid]=e/se;
      }
      __syncthreads();
      float alloc=(1.f-u)*cpl[si];          // reference's cp[si[k]] indexing
      float ag=sigf(xil[917]),wg=sigf(xil[918]);
      float wwv=wg*(ag*alloc+(1.f-ag)*wcas[n]);
      wwl[n]=wwv;
      pst(T+TF_WW+n,wwv);
      float wsum=blk_sum(wwv,s8);
      float pn=(1.f-wsum)*precl[n]+wwv;
      precl[n]=pn;
      pst(T+TF_PREC+(t&1)*Nq+n,pn);
      bump(FLAG_WW);
    }
  } else {
    // ================= LINK =================
    const int rg=l>>3, cg=l&7;
    const int n_own=g*64+w*8+rg;
    const int c0=cg*16;
    float4 m4[4]; float nrm;
    { const float4* src=(const float4*)(p.mem0+((size_t)b*Nq+n_own)*Mq+c0);
      float s=0.f;
      #pragma unroll
      for (int i=0;i<4;i++){ m4[i]=src[i]; s+=dot4(m4[i],m4[i]); }
      nrm=sqrtf(red_cg(s));
    }
    float Lreg[8][8];
    #pragma unroll
    for (int rr=0;rr<8;rr++)
      #pragma unroll
      for (int q=0;q<8;q++) Lreg[rr][q]=0.f;

    for (int t=0;t<=Tq;t++){
      // ---- reads partial ----
      waitge(FLAG_RW, (unsigned)(t+1));
      for (int i=tid;i<Rq*Nq;i+=512) rwl[i]=pld(T+TF_RW+i);
      float* prl=wcas;
      prl[tid]=0.f;
      __syncthreads();
      #pragma unroll
      for (int r=0;r<Rq;r++){
        float rwn=rwl[r*Nq+n_own];
        #pragma unroll
        for (int i=0;i<4;i++){
          float ax=rwn*m4[i].x, ay=rwn*m4[i].y, az=rwn*m4[i].z, aw=rwn*m4[i].w;
          ax+=__shfl_xor(ax,8,64); ax+=__shfl_xor(ax,16,64); ax+=__shfl_xor(ax,32,64);
          ay+=__shfl_xor(ay,8,64); ay+=__shfl_xor(ay,16,64); ay+=__shfl_xor(ay,32,64);
          az+=__shfl_xor(az,8,64); az+=__shfl_xor(az,16,64); az+=__shfl_xor(az,32,64);
          aw+=__shfl_xor(aw,8,64); aw+=__shfl_xor(aw,16,64); aw+=__shfl_xor(aw,32,64);
          if (rg==0){
            atomicAdd(&prl[r*Wq+c0+i*4+0],ax);
            atomicAdd(&prl[r*Wq+c0+i*4+1],ay);
            atomicAdd(&prl[r*Wq+c0+i*4+2],az);
            atomicAdd(&prl[r*Wq+c0+i*4+3],aw);
          }
        }
      }
      __syncthreads();
      pst(T+TF_PR+g*512+tid, prl[tid]);
      bump(CNT_RD);
      if (t==Tq) break;
      // ---- xi WK pull + wca score ----
      waitge(FLAG_XI, (unsigned)(t+1));
      if (tid<Wq) xil[512+tid]=pld(T+TF_XI+512+tid);
      if (tid<23) xil[896+tid]=pld(T+TF_XI+896+tid);
      __syncthreads();
      float keep=1.f-(float)p.rst[b*Tq+t];
      { float kk=(tid<Wq)? xil[512+tid]*xil[512+tid]:0.f;
        float kn=sqrtf(blk_sum(kk,s8));
        const float4* k4=(const float4*)(xil+512);
        float d=0.f;
        #pragma unroll
        for (int i=0;i<4;i++) d+=dot4(k4[cg*4+i],m4[i]);
        d=red_cg(d);
        float wstr=oneplusf(xil[916]);
        float sim=(keep*d)/(kn*(keep*nrm)+1e-6f);
        if (cg==0) pst(T+TF_WC+n_own, wstr*sim);
      }
      bump(CNT_WC);
      // ---- prec prefetch, wait ww, pull ww + xi rest ----
      precl[tid]=pld(T+TF_PREC+((t&1)^1)*Nq+tid);
      waitge(FLAG_WW,(unsigned)(t+1));
      wwl[tid]=pld(T+TF_WW+tid);
      xil[tid]=pld(T+TF_XI+tid);
      if (tid<256) xil[640+tid]=pld(T+TF_XI+640+tid);
      __syncthreads();
      // ---- link update (registers) + fw/bw ----
      { float* fwacc=scrA;
        int c0p=l*8;
        float ww8[8],pc8[8],pr8[Rq][8];
        *(float4*)&ww8[0]=*(const float4*)&wwl[c0p];   *(float4*)&ww8[4]=*(const float4*)&wwl[c0p+4];
        *(float4*)&pc8[0]=*(const float4*)&precl[c0p]; *(float4*)&pc8[4]=*(const float4*)&precl[c0p+4];
        #pragma unroll
        for (int r=0;r<Rq;r++){
          *(float4*)&pr8[r][0]=*(const float4*)&rwl[r*Nq+c0p];
          *(float4*)&pr8[r][4]=*(const float4*)&rwl[r*Nq+c0p+4];
        }
        float fa[Rq][8];
        #pragma unroll
        for (int r=0;r<Rq;r++)
          #pragma unroll
          for (int q=0;q<8;q++) fa[r][q]=0.f;
        #pragma unroll
        for (int rr=0;rr<8;rr++){
          int n2=g*64+w*8+rr;
          float wwn=wwl[n2];
          float prn[Rq];
          #pragma unroll
          for (int r=0;r<Rq;r++) prn[r]=rwl[r*Nq+n2];
          float bwp[Rq]={0.f,0.f,0.f,0.f};
          #pragma unroll
          for (int q=0;q<8;q++){
            float nv=(1.f-wwn-ww8[q])*Lreg[rr][q]+wwn*pc8[q];
            if (c0p+q==n2) nv=0.f;
            Lreg[rr][q]=nv;
            #pragma unroll
            for (int r=0;r<Rq;r++){ fa[r][q]+=prn[r]*nv; bwp[r]+=pr8[r][q]*nv; }
          }
          #pragma unroll
          for (int mm=1;mm<64;mm<<=1)
            #pragma unroll
            for (int r=0;r<Rq;r++) bwp[r]+=__shfl_xor(bwp[r],mm,64);
          if (l==0){
            #pragma unroll
            for (int r=0;r<Rq;r++) pst(T+TF_BW+r*Nq+n2, bwp[r]);
          }
        }
        // wave-serialized fw accumulation (no LDS atomics)
        for (int k=0;k<8;k++){
          if (w==k){
            #pragma unroll
            for (int r=0;r<Rq;r++)
              #pragma unroll
              for (int q=0;q<8;q++){
                if (k==0) fwacc[r*Nq+c0p+q]=fa[r][q];
                else      fwacc[r*Nq+c0p+q]+=fa[r][q];
              }
          }
          __syncthreads();
        }
        for (int i=tid;i<Rq*Nq;i+=512) pst(T+TF_FW+g*2048+i,fwacc[i]);
      }
      bump(CNT_LNK);   // fw/bw ready — alpha starts its big pull now
      // ---- mem update (registers) + new norm + rca scores ----
      { float wwn=wwl[n_own];
        float s=0.f;
        #pragma unroll
        for (int i=0;i<4;i++){
          float e0=sigf(xil[768+c0+i*4+0]), e1=sigf(xil[768+c0+i*4+1]);
          float e2=sigf(xil[768+c0+i*4+2]), e3=sigf(xil[768+c0+i*4+3]);
          m4[i].x=m4[i].x*keep*(1.f-wwn*e0)+wwn*xil[640+c0+i*4+0];
          m4[i].y=m4[i].y*keep*(1.f-wwn*e1)+wwn*xil[640+c0+i*4+1];
          m4[i].z=m4[i].z*keep*(1.f-wwn*e2)+wwn*xil[640+c0+i*4+2];
          m4[i].w=m4[i].w*keep*(1.f-wwn*e3)+wwn*xil[640+c0+i*4+3];
          s+=dot4(m4[i],m4[i]);
        }
        nrm=sqrtf(red_cg(s));
        float kn4[Rq], rstr[Rq];
        #pragma unroll
        for (int r=0;r<Rq;r++){
          float kk=(tid<Wq)? xil[r*Wq+tid]*xil[r*Wq+tid]:0.f;
          kn4[r]=sqrtf(blk_sum(kk,s8));
          rstr[r]=oneplusf(xil[900+r]);
        }
        #pragma unroll
        for (int r=0;r<Rq;r++){
          const float4* kr=(const float4*)(xil+r*Wq);
          float d=0.f;
          #pragma unroll
          for (int i=0;i<4;i++) d+=dot4(kr[cg*4+i],m4[i]);
          d=red_cg(d);
          float v=rstr[r]*(d/(kn4[r]*nrm+1e-6f));
          if (cg==0) pst(T+TF_RCA+r*Nq+n_own, v);
        }
      }
      bump(CNT_FW);
    }
  }
}

// ---------- k_y: all outputs y[b][t][j] ----------
__global__ __launch_bounds__(512) void k_y(P p){
  int j=blockIdx.x, tid=threadIdx.x;
  __shared__ __align__(16) float wv[Wq];
  __shared__ __align__(16) float wr[Rq*Wq];
  if (tid<Wq) wv[tid]=p.WvT[(size_t)j*Wq+tid];
  wr[tid]=p.WrT[(size_t)j*(Rq*Wq)+tid];
  __syncthreads();
  int b=tid>>5, t=tid&31;
  const float4* h4=(const float4*)(p.out+BTWq+((size_t)b*Tq+t)*Wq);
  const float4* r4=(const float4*)(p.rdh+((size_t)b*Tq+t)*Nq);
  const float4* wv4=(const float4*)wv;
  const float4* wr4=(const float4*)wr;
  float a=0.f;
  #pragma unroll 8
  for (int c=0;c<32;c++) a+=dot4(wv4[c],h4[c]);
  #pragma unroll 8
  for (int c=0;c<128;c++) a+=dot4(wr4[c],r4[c]);
  p.out[((size_t)b*Tq+t)*Wq+j]=a+p.bv[j]+p.br[j];
}

extern "C" void kernel_launch(void* const* d_in, const int* in_sizes, int n_in,
                              void* d_out, int out_size, void* d_ws, size_t ws_size,
                              hipStream_t stream){
  (void)in_sizes; (void)n_in; (void)out_size; (void)ws_size;
  P p;
  p.X    = (const float*)d_in[0];
  p.hs0  = (const float*)d_in[1];
  p.mem0 = (const float*)d_in[2];
  p.rst  = (const int*)d_in[3];
  p.Wb   = (const float*)d_in[4];  p.bb   = (const float*)d_in[5];
  p.Wff1 = (const float*)d_in[6];  p.bff1 = (const float*)d_in[7];
  p.Wff2 = (const float*)d_in[8];  p.bff2 = (const float*)d_in[9];
  p.Wta  = (const float*)d_in[10]; p.bta  = (const float*)d_in[11];
  p.Wtb  = (const float*)d_in[12]; p.btb  = (const float*)d_in[13];
  p.Wv   = (const float*)d_in[14]; p.bv   = (const float*)d_in[15];
  p.Wr   = (const float*)d_in[16]; p.br   = (const float*)d_in[17];
  p.Wxi  = (const float*)d_in[18]; p.bxi  = (const float*)d_in[19];
  p.out  = (float*)d_out;
  float* ws = (float*)d_ws;
  size_t o = 0;
  p.rdh   = ws + o; o += (size_t)Bq*Tq*Nq;    //   262,144
  p.teams = ws + o; o += (size_t)16*TSTRIDE;  //   499,712
  p.WbT   = ws + o; o += (size_t)DINq*Wq;
  p.Wff1T = ws + o; o += (size_t)Wq*Wq;
  p.Wff2T = ws + o; o += (size_t)Wq*Wq;
  p.WtaT  = ws + o; o += (size_t)Wq*Wq;
  p.WtbT  = ws + o; o += (size_t)Wq*Wq;
  p.WvT   = ws + o; o += (size_t)Wq*Wq;
  p.WrT   = ws + o; o += (size_t)Rq*Wq*Wq;
  p.WxiT  = ws + o; o += (size_t)XIDq*Wq;

  hipLaunchKernelGGL(k_init, dim3(38),  dim3(256), 0, stream, p);
  hipLaunchKernelGGL(k_run,  dim3(144), dim3(512), 0, stream, p);
  hipLaunchKernelGGL(k_y,    dim3(128), dim3(512), 0, stream, p);
}